// Round 2
// baseline (94.993 us; speedup 1.0000x reference)
//
#include <hip/hip_runtime.h>

// NURBS surface evaluation, MI355X — separable two-stage blend.
// Inputs:  cp (256,256,3) f32, kvx (1,260) f32, kvy (1,260) f32
// Output:  (1,1024,1024,3) f32
//
// prep:   normalize knots (sequential cumsum preserving numpy fp order),
//         spans via binary search (searchsorted side='right'), Cox-de-Boor
//         basis with mod-260 knot wrap, mod-256 control indices.
// stage1: T[i,f,:] = sum_r by[f,r] * cp[i, iy[f,r], :]   (1 gather/pixel total)
// stage2: out[e,f,:] = sum_l bx[e,l] * T[ix[e,l], f, :]  (no gathers, float4 I/O)

#define KLEN  260
#define NCTRL 256
#define OUTN  1024
#define DEG   3
#define EPSV  1e-5

__global__ __launch_bounds__(256) void nurbs_prep(
    const float* __restrict__ kvx, const float* __restrict__ kvy,
    float4* __restrict__ bx4, int4* __restrict__ ix4,
    float4* __restrict__ by4, int4* __restrict__ iy4) {
  __shared__ float kn[2][KLEN];
  const int t = threadIdx.x;

  for (int i = t; i < KLEN; i += 256) {
    kn[0][i] = kvx[i];
    kn[1][i] = kvy[i];
  }
  __syncthreads();

  // Sequential cumsum + normalize; serial on purpose (numpy fp add order).
  if (t < 2) {
    float* a = kn[t];
    float run = 0.f;
    #pragma unroll 4
    for (int i = 0; i < KLEN; ++i) {
      float v = a[i];
      v = (v < 0.f) ? 1e-4f : v;
      run += v;
      a[i] = run;
    }
    const float c0 = a[0];
    const float d  = a[KLEN - 1] - c0;
    #pragma unroll 4
    for (int i = 0; i < KLEN; ++i) a[i] = (a[i] - c0) / d;
  }
  __syncthreads();

  const double step = (1.0 - 2.0 * (double)EPSV) / (double)(OUTN - 1);

  for (int item = t; item < 2 * OUTN; item += 256) {
    const int which = item >> 10;      // 0 = x axis, 1 = y axis
    const int idx   = item & (OUTN - 1);
    const float* k  = kn[which];
    const float u   = (float)((double)EPSV + (double)idx * step);

    // searchsorted(k, u, side='right') - 1
    int lo = 0, hi = KLEN;
    while (lo < hi) {
      int mid = (lo + hi) >> 1;
      if (k[mid] <= u) lo = mid + 1; else hi = mid;
    }
    int span = lo - 1;
    if (u == k[NCTRL]) span = NCTRL - 1;

    float left[DEG + 1], right[DEG + 1], cols[DEG + 1];
    cols[0] = 1.f;
    #pragma unroll
    for (int j = 1; j <= DEG; ++j) {
      int li = span + 1 - j; li %= KLEN; if (li < 0) li += KLEN;
      int ri = (span + j) % KLEN;
      left[j]  = u - k[li];
      right[j] = k[ri] - u;
      float saved = 0.f;
      #pragma unroll
      for (int r = 0; r < j; ++r) {
        float temp = cols[r] / (right[r + 1] + left[j - r]);
        cols[r] = saved + right[r + 1] * temp;
        saved = left[j - r] * temp;
      }
      cols[j] = saved;
    }

    float4 b; b.x = cols[0]; b.y = cols[1]; b.z = cols[2]; b.w = cols[3];
    int4 ii;
    ii.x = (span - DEG + 0) & (NCTRL - 1);
    ii.y = (span - DEG + 1) & (NCTRL - 1);
    ii.z = (span - DEG + 2) & (NCTRL - 1);
    ii.w = (span - DEG + 3) & (NCTRL - 1);

    if (which == 0) { bx4[idx] = b; ix4[idx] = ii; }
    else            { by4[idx] = b; iy4[idx] = ii; }
  }
}

// T[i, f, d] = sum_r by[f,r] * cp[i, iy[f,r], d]
// grid (4, 256), block 256: i = blockIdx.y (row is 3KB, L1-resident),
// f coalesced across threads. 4 gathers x 12B per thread.
__global__ __launch_bounds__(256) void nurbs_stage1(
    const float* __restrict__ cp,
    const float4* __restrict__ by4, const int4* __restrict__ iy4,
    float* __restrict__ T) {
  const int f = (blockIdx.x << 8) + threadIdx.x;
  const int i = blockIdx.y;

  const float4 w = by4[f];
  const int4   r = iy4[f];
  const float* row = cp + i * (NCTRL * 3);

  const float* p0 = row + r.x * 3;
  const float* p1 = row + r.y * 3;
  const float* p2 = row + r.z * 3;
  const float* p3 = row + r.w * 3;

  float ax = w.x * p0[0] + w.y * p1[0] + w.z * p2[0] + w.w * p3[0];
  float ay = w.x * p0[1] + w.y * p1[1] + w.z * p2[1] + w.w * p3[1];
  float az = w.x * p0[2] + w.y * p1[2] + w.z * p2[2] + w.w * p3[2];

  float* o = T + i * (OUTN * 3) + f * 3;
  o[0] = ax; o[1] = ay; o[2] = az;
}

// out[e, f, d] = sum_l bx[e,l] * T[ix[e,l], f, d]
// grid 1024, block 256: e = blockIdx.x (bx/ix wave-uniform), each thread
// handles 4 consecutive f via 3 float4 chunks per row. Pure streaming.
__global__ __launch_bounds__(256) void nurbs_stage2(
    const float* __restrict__ T,
    const float4* __restrict__ bx4, const int4* __restrict__ ix4,
    float4* __restrict__ out4) {
  const int e = blockIdx.x;
  const int t = threadIdx.x;

  const float4 w = bx4[e];
  const int4   r = ix4[e];

  const float4* r0 = (const float4*)(T + r.x * (OUTN * 3));
  const float4* r1 = (const float4*)(T + r.y * (OUTN * 3));
  const float4* r2 = (const float4*)(T + r.z * (OUTN * 3));
  const float4* r3 = (const float4*)(T + r.w * (OUTN * 3));

  float4* o = out4 + e * (OUTN * 3 / 4);

  #pragma unroll
  for (int j = 0; j < 3; ++j) {
    const int idx = t * 3 + j;
    const float4 a = r0[idx];
    const float4 b = r1[idx];
    const float4 c = r2[idx];
    const float4 d = r3[idx];
    float4 v;
    v.x = w.x * a.x + w.y * b.x + w.z * c.x + w.w * d.x;
    v.y = w.x * a.y + w.y * b.y + w.z * c.y + w.w * d.y;
    v.z = w.x * a.z + w.y * b.z + w.z * c.z + w.w * d.z;
    v.w = w.x * a.w + w.y * b.w + w.z * c.w + w.w * d.w;
    o[idx] = v;
  }
}

extern "C" void kernel_launch(void* const* d_in, const int* in_sizes, int n_in,
                              void* d_out, int out_size, void* d_ws, size_t ws_size,
                              hipStream_t stream) {
  (void)in_sizes; (void)n_in; (void)out_size; (void)ws_size;
  const float* cp  = (const float*)d_in[0];
  const float* kvx = (const float*)d_in[1];
  const float* kvy = (const float*)d_in[2];

  char* ws = (char*)d_ws;
  float4* bx4 = (float4*)(ws);            // 1024 * 16 B
  int4*   ix4 = (int4*)  (ws + 16384);
  float4* by4 = (float4*)(ws + 32768);
  int4*   iy4 = (int4*)  (ws + 49152);
  float*  T   = (float*) (ws + 65536);    // 256*1024*3 floats = 3 MB

  nurbs_prep<<<1, 256, 0, stream>>>(kvx, kvy, bx4, ix4, by4, iy4);
  nurbs_stage1<<<dim3(4, 256), 256, 0, stream>>>(cp, by4, iy4, T);
  nurbs_stage2<<<1024, 256, 0, stream>>>(T, bx4, ix4, (float4*)d_out);
}

// Round 3
// 74.445 us; speedup vs baseline: 1.2760x; 1.2760x over previous
//
#include <hip/hip_runtime.h>

// NURBS surface evaluation, MI355X — single fused kernel.
// Inputs:  cp (256,256,3) f32, kvx (1,260) f32, kvy (1,260) f32
// Output:  (1,1024,1024,3) f32
//
// Every block independently:
//  1. normalizes both knot vectors (clamp<0 -> 1e-4, blocked shfl-scan cumsum,
//     affine normalize) into LDS. Parallel-scan reassociation perturbs knots
//     ~1e-7 rel; output perturbation ~1e-6, far under the 6.3e-2 threshold.
//  2. computes Cox-de-Boor basis + wrapped control indices for its one e
//     (block-uniform) and its 256 f values (one per thread), in registers.
//  3. 4x4 weighted blend of control points (768KB table, L2-resident;
//     e fixed per block, f-adjacent lanes hit the same cache lines).
//  4. repacks through LDS, stores coalesced float4.
// One dispatch total (was 3) — the bench floor is harness reset fills.

#define KLEN  260
#define NCTRL 256
#define OUTN  1024
#define DEG   3
#define EPSV  1e-5
#define CHUNK 5   // 52 lanes x 5 = 260 knots per wave

__device__ __forceinline__ void basis_eval(const float* __restrict__ k,
                                           int idx, float* w, int* ci) {
  const double step = (1.0 - 2.0 * (double)EPSV) / (double)(OUTN - 1);
  const float u = (float)((double)EPSV + (double)idx * step);

  // searchsorted(k, u, side='right') - 1
  int lo = 0, hi = KLEN;
  while (lo < hi) {
    int mid = (lo + hi) >> 1;
    if (k[mid] <= u) lo = mid + 1; else hi = mid;
  }
  int span = lo - 1;
  if (u == k[NCTRL]) span = NCTRL - 1;

  float left[DEG + 1], right[DEG + 1], cols[DEG + 1];
  cols[0] = 1.f;
  #pragma unroll
  for (int j = 1; j <= DEG; ++j) {
    int li = span + 1 - j; li %= KLEN; if (li < 0) li += KLEN;
    int ri = (span + j) % KLEN;
    left[j]  = u - k[li];
    right[j] = k[ri] - u;
    float saved = 0.f;
    #pragma unroll
    for (int r = 0; r < j; ++r) {
      float temp = cols[r] / (right[r + 1] + left[j - r]);
      cols[r] = saved + right[r + 1] * temp;
      saved = left[j - r] * temp;
    }
    cols[j] = saved;
  }
  #pragma unroll
  for (int l = 0; l <= DEG; ++l) {
    w[l]  = cols[l];
    ci[l] = (span - DEG + l) & (NCTRL - 1);
  }
}

__global__ __launch_bounds__(256) void nurbs_fused(
    const float* __restrict__ cp,
    const float* __restrict__ kvx, const float* __restrict__ kvy,
    float* __restrict__ out) {
  __shared__ float kn[2][KLEN];
  __shared__ float sbuf[256 * 3];

  const int t    = threadIdx.x;
  const int wave = t >> 6;
  const int lane = t & 63;

  // ---- knot normalization: wave 0 -> x knots, wave 1 -> y knots ----
  if (wave < 2) {
    const float* kv = (wave == 0) ? kvx : kvy;
    float v[CHUNK];
    float lsum = 0.f;
    if (lane < 52) {
      #pragma unroll
      for (int j = 0; j < CHUNK; ++j) {
        float x = kv[lane * CHUNK + j];
        x = (x < 0.f) ? 1e-4f : x;
        v[j] = x;
        lsum += x;
      }
    } else {
      #pragma unroll
      for (int j = 0; j < CHUNK; ++j) v[j] = 0.f;
    }
    // inclusive shfl scan of per-lane sums (wave64)
    float s = lsum;
    #pragma unroll
    for (int d = 1; d < 64; d <<= 1) {
      float n = __shfl_up(s, d);
      if (lane >= d) s += n;
    }
    const float excl  = s - lsum;
    const float total = __shfl(s, 51);     // cumsum[KLEN-1]
    const float c0    = __shfl(v[0], 0);   // cumsum[0]
    const float inv_d = 1.f / (total - c0);
    if (lane < 52) {
      float run = excl;
      #pragma unroll
      for (int j = 0; j < CHUNK; ++j) {
        run += v[j];
        kn[wave][lane * CHUNK + j] = (run - c0) * inv_d;
      }
    }
  }
  __syncthreads();

  const int bx    = blockIdx.x;
  const int e     = bx >> 2;
  const int fbase = (bx & 3) << 8;
  const int f     = fbase + t;

  float wE[4], wF[4];
  int   iE[4], iF[4];
  basis_eval(kn[0], e, wE, iE);   // block-uniform
  basis_eval(kn[1], f, wF, iF);   // per-thread

  float ax = 0.f, ay = 0.f, az = 0.f;
  #pragma unroll
  for (int l = 0; l < 4; ++l) {
    const float* rowp = cp + iE[l] * (NCTRL * 3);
    const float wl = wE[l];
    #pragma unroll
    for (int r = 0; r < 4; ++r) {
      const float w = wl * wF[r];
      const float* p = rowp + iF[r] * 3;
      ax += w * p[0];
      ay += w * p[1];
      az += w * p[2];
    }
  }

  // repack through LDS -> coalesced float4 stores (stride-3 LDS is odd: no conflicts)
  sbuf[t * 3 + 0] = ax;
  sbuf[t * 3 + 1] = ay;
  sbuf[t * 3 + 2] = az;
  __syncthreads();

  float4* ob = (float4*)(out + (size_t)(e * OUTN + fbase) * 3);
  if (t < 192) ob[t] = ((const float4*)sbuf)[t];
}

extern "C" void kernel_launch(void* const* d_in, const int* in_sizes, int n_in,
                              void* d_out, int out_size, void* d_ws, size_t ws_size,
                              hipStream_t stream) {
  (void)in_sizes; (void)n_in; (void)out_size; (void)d_ws; (void)ws_size;
  const float* cp  = (const float*)d_in[0];
  const float* kvx = (const float*)d_in[1];
  const float* kvy = (const float*)d_in[2];
  float* out = (float*)d_out;

  nurbs_fused<<<4096, 256, 0, stream>>>(cp, kvx, kvy, out);
}